// Round 7
// baseline (473.708 us; speedup 1.0000x reference)
//
#include <hip/hip_runtime.h>
#include <math.h>

#define DE 128
#define NEG_SLOPE 0.2f
#define LOG2E 1.4426950408889634f
#define ESHIFT2 57.707801635559926f  /* 40 * log2(e) */

typedef __attribute__((ext_vector_type(4))) float f4;
typedef __attribute__((ext_vector_type(2))) float f2;
typedef _Float16 half_t;
typedef __attribute__((ext_vector_type(2))) _Float16 h2;
typedef __attribute__((ext_vector_type(4))) _Float16 h4v;
typedef __attribute__((ext_vector_type(8))) _Float16 h8;

// All-reduce over each 16-lane DPP row via ROW_ROR rotations: after adds of
// rotations by 1,2,4,8 every lane of the row holds the row's total. 4 DPP adds,
// no readlane, no broadcast, zero LDS-pipe traffic.
__device__ __forceinline__ float row16_allred(float x) {
    union fi { float f; int i; };
    fi a; a.f = x;
    fi t;
    t.i = __builtin_amdgcn_update_dpp(0, a.i, 0x121, 0xf, 0xf, true); a.f += t.f; // row_ror:1
    t.i = __builtin_amdgcn_update_dpp(0, a.i, 0x122, 0xf, 0xf, true); a.f += t.f; // row_ror:2
    t.i = __builtin_amdgcn_update_dpp(0, a.i, 0x124, 0xf, 0xf, true); a.f += t.f; // row_ror:4
    t.i = __builtin_amdgcn_update_dpp(0, a.i, 0x128, 0xf, 0xf, true); a.f += t.f; // row_ror:8
    return a.f;
}

// ---------------------------------------------------------------- CSR build
__global__ __launch_bounds__(256) void k_count(const int* __restrict__ ei, int E, int N,
                                               int* __restrict__ cnt) {
    int e = blockIdx.x * blockDim.x + threadIdx.x;
    int total = E + N;
    if (e >= total) return;
    int dst = (e < E) ? ei[E + e] : (e - E);
    atomicAdd(&cnt[dst], 1);
}

__global__ __launch_bounds__(1024) void k_scan(const int* __restrict__ cnt, int n,
                                               int* __restrict__ indptr) {
    __shared__ int wsum[16];
    __shared__ int btot;
    int tid = threadIdx.x, lane = tid & 63, w = tid >> 6;
    int carry = 0;
    for (int base = 0; base < n; base += 1024) {
        int i = base + tid;
        int v = (i < n) ? cnt[i] : 0;
        int x = v;
#pragma unroll
        for (int off = 1; off < 64; off <<= 1) {
            int t = __shfl_up(x, off, 64);
            if (lane >= off) x += t;
        }
        if (lane == 63) wsum[w] = x;
        __syncthreads();
        if (w == 0) {
            int s = (lane < 16) ? wsum[lane] : 0;
#pragma unroll
            for (int off = 1; off < 16; off <<= 1) {
                int t = __shfl_up(s, off, 64);
                if (lane >= off) s += t;
            }
            if (lane < 16) wsum[lane] = s;
            if (lane == 15) btot = s;
        }
        __syncthreads();
        int wexcl = (w == 0) ? 0 : wsum[w - 1];
        if (i < n) indptr[i] = carry + wexcl + (x - v);
        carry += btot;
        __syncthreads();
    }
    if (tid == 0) indptr[n] = carry;
}

__global__ __launch_bounds__(256) void k_fill(const int* __restrict__ ei, int E, int N,
                                              const int* __restrict__ indptr,
                                              int* __restrict__ cur, int* __restrict__ adj) {
    int e = blockIdx.x * blockDim.x + threadIdx.x;
    int total = E + N;
    if (e >= total) return;
    int src, dst;
    if (e < E) { src = ei[e]; dst = ei[E + e]; }
    else       { src = dst = e - E; }
    int pos = indptr[dst] + atomicAdd(&cur[dst], 1);
    adj[pos] = src;
}

// ---------------------------------------------------------------- GEMM
// out[r][c] = sum_k in[r][k] * W[c*ldw + wcol0 + k]  (+bias) (+addtab[addidx[r]])
// Optional: f32 out, fp16 out16 (either may be null), fused alpha epilogue.
template <int RPT>
__global__ __launch_bounds__(256) void k_gemm(const float* __restrict__ in, int rows,
                                              const float* __restrict__ W, int ldw, int wcol0,
                                              const float* __restrict__ bias,
                                              const float* __restrict__ addtab,
                                              const int* __restrict__ addidx,
                                              const float* __restrict__ avs,
                                              const float* __restrict__ avd,
                                              float* __restrict__ als,
                                              float* __restrict__ ald,
                                              float* __restrict__ out,
                                              half_t* __restrict__ out16) {
    __shared__ float Wt[128 * 128];  // Wt[k*128+c]; b128 row reads are 2-way aliased = free
    const int tid = threadIdx.x;
#pragma unroll
    for (int it = 0; it < 16; ++it) {
        int idx = it * 256 + tid;
        int c = idx & 127, k4 = idx >> 7;
        f4 wv = *(const f4*)(W + (size_t)c * ldw + wcol0 + k4 * 4);
#pragma unroll
        for (int j = 0; j < 4; ++j) Wt[(4 * k4 + j) * 128 + c] = wv[j];
    }
    __syncthreads();

    const int cgrp = tid & 15, rgrp = tid >> 4;
    const int c0 = cgrp * 4;
    const int row0 = blockIdx.x * (16 * RPT) + rgrp * RPT;

    const float* rowp[RPT];
#pragma unroll
    for (int i = 0; i < RPT; ++i)
        rowp[i] = in + (size_t)min(row0 + i, rows - 1) * 128;

    float acc[RPT][8];
#pragma unroll
    for (int i = 0; i < RPT; ++i)
#pragma unroll
        for (int j = 0; j < 8; ++j) acc[i][j] = 0.f;

    f4 a0[RPT], a1[RPT];
#pragma unroll
    for (int i = 0; i < RPT; ++i) a0[i] = *(const f4*)(rowp[i] + 0);

#pragma unroll 1
    for (int k = 0; k < 128; k += 8) {
#pragma unroll
        for (int i = 0; i < RPT; ++i) a1[i] = *(const f4*)(rowp[i] + k + 4);
#pragma unroll
        for (int kk = 0; kk < 4; ++kk) {
            f4 b0 = *(const f4*)&Wt[(k + kk) * 128 + c0];
            f4 b1 = *(const f4*)&Wt[(k + kk) * 128 + c0 + 64];
#pragma unroll
            for (int i = 0; i < RPT; ++i) {
                float a = a0[i][kk];
#pragma unroll
                for (int j = 0; j < 4; ++j) {
                    acc[i][j]     = fmaf(a, b0[j], acc[i][j]);
                    acc[i][j + 4] = fmaf(a, b1[j], acc[i][j + 4]);
                }
            }
        }
        int k2 = (k + 8) & 127;  // wraps on last iter; dead value
#pragma unroll
        for (int i = 0; i < RPT; ++i) a0[i] = *(const f4*)(rowp[i] + k2);
#pragma unroll
        for (int kk = 0; kk < 4; ++kk) {
            f4 b0 = *(const f4*)&Wt[(k + 4 + kk) * 128 + c0];
            f4 b1 = *(const f4*)&Wt[(k + 4 + kk) * 128 + c0 + 64];
#pragma unroll
            for (int i = 0; i < RPT; ++i) {
                float a = a1[i][kk];
#pragma unroll
                for (int j = 0; j < 4; ++j) {
                    acc[i][j]     = fmaf(a, b0[j], acc[i][j]);
                    acc[i][j + 4] = fmaf(a, b1[j], acc[i][j + 4]);
                }
            }
        }
    }

    f4 bi0 = {0.f, 0.f, 0.f, 0.f}, bi1 = {0.f, 0.f, 0.f, 0.f};
    if (bias) { bi0 = *(const f4*)(bias + c0); bi1 = *(const f4*)(bias + c0 + 64); }
    f4 as0 = {0.f,0.f,0.f,0.f}, as1 = as0, ad0 = as0, ad1 = as0;
    if (als) {
        as0 = *(const f4*)(avs + c0); as1 = *(const f4*)(avs + c0 + 64);
        ad0 = *(const f4*)(avd + c0); ad1 = *(const f4*)(avd + c0 + 64);
    }
#pragma unroll
    for (int i = 0; i < RPT; ++i) {
        int r = row0 + i;
        f4 v0, v1;
#pragma unroll
        for (int j = 0; j < 4; ++j) { v0[j] = acc[i][j] + bi0[j]; v1[j] = acc[i][j + 4] + bi1[j]; }
        if (addtab) {
            int ri = addidx[min(r, rows - 1)];
            v0 += *(const f4*)(addtab + (size_t)ri * 128 + c0);
            v1 += *(const f4*)(addtab + (size_t)ri * 128 + c0 + 64);
        }
        if (als) {
            float ps = 0.f, pd = 0.f;
#pragma unroll
            for (int j = 0; j < 4; ++j) {
                ps += v0[j] * as0[j] + v1[j] * as1[j];
                pd += v0[j] * ad0[j] + v1[j] * ad1[j];
            }
#pragma unroll
            for (int off = 1; off < 16; off <<= 1) {
                ps += __shfl_xor(ps, off, 64);
                pd += __shfl_xor(pd, off, 64);
            }
            if (cgrp == 0 && r < rows) { als[r] = ps; ald[r] = pd; }
        }
        if (r < rows) {
            if (out) {
                *(f4*)(out + (size_t)r * 128 + c0) = v0;
                *(f4*)(out + (size_t)r * 128 + c0 + 64) = v1;
            }
            if (out16) {
                h4v o0 = {(half_t)v0[0], (half_t)v0[1], (half_t)v0[2], (half_t)v0[3]};
                h4v o1 = {(half_t)v1[0], (half_t)v1[1], (half_t)v1[2], (half_t)v1[3]};
                *(h4v*)(out16 + (size_t)r * 128 + c0) = o0;
                *(h4v*)(out16 + (size_t)r * 128 + c0 + 64) = o1;
            }
        }
    }
}

// ---------------------------------------------------------------- entity attention
// 4 nodes per wave, 16 lanes per node, lane owns 8 contiguous cols (b128 fp16
// gathers). Score/accum via v_fma_mix; cross-lane reduce = 4 ROW_ROR DPP adds.
// Softmax shift (40) folded into lane 0's dot partial (init), weights = raw
// v_exp. Register discipline: explicit A/B pair double-buffer, #pragma unroll 1
// outer loop -> <=8 gathers in flight (32 VGPR of buffers), occupancy restored.
__global__ __launch_bounds__(256, 5) void k_entity(const int* __restrict__ hA,
                                                   const int* __restrict__ tA,
                                                   const int* __restrict__ ridx,
                                                   const half_t* __restrict__ pattr,
                                                   const float* __restrict__ prel,
                                                   float* __restrict__ s_emb, int N) {
    const int tid = threadIdx.x;
    const int node0 = (blockIdx.x * 256 + tid) >> 4;  // 16-lane group = node
    const int gl = tid & 15;
    const bool active = node0 < N;
    const int node = active ? node0 : N - 1;
    const int co = gl * 8;                            // first of 8 owned cols

    const int* __restrict__ hp = hA + (size_t)node * 16;
    const int* __restrict__ tp = tA + (size_t)node * 16;
    const int ri = ridx[node];

    // rp slice (8 cols), pre-scaled by log2(e) so weights use raw exp2
    float rpf[8];
    {
        f4 rA = *(const f4*)(prel + (size_t)ri * 128 + co);
        f4 rB = *(const f4*)(prel + (size_t)ri * 128 + co + 4);
#pragma unroll
        for (int j = 0; j < 4; ++j) { rpf[j] = rA[j] * LOG2E; rpf[4 + j] = rB[j] * LOG2E; }
    }
    const float init = (gl == 0) ? -ESHIFT2 : 0.f;  // shift enters the dot ONCE per row

    float sh = 0.f, st = 0.f;
    float acch[8], acct[8];
#pragma unroll
    for (int j = 0; j < 8; ++j) { acch[j] = 0.f; acct[j] = 0.f; }

    auto ld = [&](int idx) -> h8 { return *(const h8*)(pattr + (size_t)idx * 128 + co); };
    auto erow = [&](const h8& v, float* acc, float& ssum) {
        float p0 = init, p1 = 0.f;
#pragma unroll
        for (int j = 0; j < 4; ++j) {
            p0 = fmaf((float)v[2 * j],     rpf[2 * j],     p0);   // v_fma_mix
            p1 = fmaf((float)v[2 * j + 1], rpf[2 * j + 1], p1);
        }
        float we = exp2f(row16_allred(p0 + p1));  // v_exp_f32
        ssum += we;
#pragma unroll
        for (int j = 0; j < 8; ++j) acc[j] = fmaf(we, (float)v[j], acc[j]);
    };

    // pair = 2 rows of both sides (4 x b128). A/B double-buffer, 4 iterations:
    // rows (0,1)A (2,3)B (4,5)A (6,7)B (8,9)A (10,11)B (12,13)A (14,15)B
    int2 ih = *(const int2*)(hp), it = *(const int2*)(tp);
    h8 a_h0 = ld(ih.x), a_h1 = ld(ih.y), a_t0 = ld(it.x), a_t1 = ld(it.y);
#pragma unroll 1
    for (int b = 0; b < 4; ++b) {
        int rB = 4 * b + 2;
        int2 ihB = *(const int2*)(hp + rB), itB = *(const int2*)(tp + rB);
        h8 b_h0 = ld(ihB.x), b_h1 = ld(ihB.y), b_t0 = ld(itB.x), b_t1 = ld(itB.y);
        erow(a_h0, acch, sh); erow(a_h1, acch, sh);
        erow(a_t0, acct, st); erow(a_t1, acct, st);
        int rA = (4 * b + 4) & 15;  // wraps to 0,1 on last iter; harmless reload
        int2 ihA = *(const int2*)(hp + rA), itA = *(const int2*)(tp + rA);
        a_h0 = ld(ihA.x); a_h1 = ld(ihA.y); a_t0 = ld(itA.x); a_t1 = ld(itA.y);
        erow(b_h0, acch, sh); erow(b_h1, acch, sh);
        erow(b_t0, acct, st); erow(b_t1, acct, st);
    }

    if (active) {
        float invh = 1.f / sh, invt = 1.f / st;
        f4 o0, o1;
#pragma unroll
        for (int j = 0; j < 4; ++j) {
            o0[j] = acch[j] * invh + acct[j] * invt;
            o1[j] = acch[4 + j] * invh + acct[4 + j] * invt;
        }
        *(f4*)(s_emb + (size_t)node0 * 128 + co) = o0;
        *(f4*)(s_emb + (size_t)node0 * 128 + co + 4) = o1;
    }
}

// ---------------------------------------------------------------- GAT aggregate (CSR)
// Wave-uniform edge loop: adj[j] and als[s] are uniform -> scalar s_loads (SMEM
// pipe, batched x8); leaky-relu/exp computed wave-uniformly on VALU; row gather
// is SGPR-base + lane-offset. ZERO cross-lane (DS) ops. Single pass,
// shift-invariant softmax with fixed shift 20 (e bounded ~|15|; self-loop keeps
// the denominator alive).
__global__ __launch_bounds__(256) void k_aggregate(const int* __restrict__ indptr,
                                                   const int* __restrict__ adj,
                                                   const half_t* __restrict__ hsrc,
                                                   const float* __restrict__ als,
                                                   const float* __restrict__ ald,
                                                   const float* __restrict__ bias,
                                                   float* __restrict__ out, int N) {
    int w = (blockIdx.x * blockDim.x + threadIdx.x) >> 6;
    if (w >= N) return;
    w = __builtin_amdgcn_readfirstlane(w);
    const int lane = threadIdx.x & 63;
    const int c = lane * 2;
    const int beg = indptr[w], end = indptr[w + 1];
    const float adn = ald[w];
    float acc0 = 0.f, acc1 = 0.f, exsum = 0.f;
    int j = beg;
    for (; j + 8 <= end; j += 8) {
        int s[8];
#pragma unroll
        for (int q = 0; q < 8; ++q) s[q] = adj[j + q];        // s_load_dwordx8
        float ex[8];
#pragma unroll
        for (int q = 0; q < 8; ++q) {
            float e = als[s[q]] + adn;                        // s_load + uniform VALU
            e = fmaxf(e, NEG_SLOPE * e);                      // leaky-relu
            ex[q] = __expf(e - 20.f);
        }
        h2 v[8];
#pragma unroll
        for (int q = 0; q < 8; ++q)
            v[q] = *(const h2*)(hsrc + (size_t)s[q] * 128 + c);  // saddr + lane offset
#pragma unroll
        for (int q = 0; q < 8; ++q) {
            exsum += ex[q];
            acc0 = fmaf(ex[q], (float)v[q][0], acc0);
            acc1 = fmaf(ex[q], (float)v[q][1], acc1);
        }
    }
    for (; j < end; ++j) {
        int s = adj[j];
        float e = als[s] + adn;
        e = fmaxf(e, NEG_SLOPE * e);
        float ex = __expf(e - 20.f);
        exsum += ex;
        h2 v = *(const h2*)(hsrc + (size_t)s * 128 + c);
        acc0 = fmaf(ex, (float)v[0], acc0);
        acc1 = fmaf(ex, (float)v[1], acc1);
    }
    float inv = 1.f / exsum;
    f2 outv;
    outv[0] = fmaf(acc0, inv, bias[c]);
    outv[1] = fmaf(acc1, inv, bias[c + 1]);
    *(f2*)(out + (size_t)w * 128 + c) = outv;
}

// ---------------------------------------------------------------- launch
extern "C" void kernel_launch(void* const* d_in, const int* in_sizes, int n_in,
                              void* d_out, int out_size, void* d_ws, size_t ws_size,
                              hipStream_t stream) {
    const int*   hA   = (const int*)d_in[0];
    const int*   tA   = (const int*)d_in[1];
    const int*   rix  = (const int*)d_in[2];
    const int*   ei   = (const int*)d_in[3];
    const float* attr_table = (const float*)d_in[4];
    const float* rel_table  = (const float*)d_in[5];
    const float* femb_w = (const float*)d_in[6];
    const float* femb_b = (const float*)d_in[7];
    const float* g1w  = (const float*)d_in[8];
    const float* g1as = (const float*)d_in[9];
    const float* g1ad = (const float*)d_in[10];
    const float* g1b  = (const float*)d_in[11];
    const float* g2w  = (const float*)d_in[12];
    const float* g2as = (const float*)d_in[13];
    const float* g2ad = (const float*)d_in[14];
    const float* g2b  = (const float*)d_in[15];

    const int N  = in_sizes[2];
    const int E  = in_sizes[3] / 2;
    const int NA = in_sizes[4] / DE;
    const int NR = in_sizes[5] / DE;
    const int EN = E + N;

    char* p = (char*)d_ws;
    auto alloc = [&](size_t bytes) -> char* {
        char* q = p;
        p += (bytes + 255) & ~(size_t)255;
        return q;
    };
    half_t* proj16 = (half_t*)alloc((size_t)NA * DE * 2);
    half_t* h16    = (half_t*)alloc((size_t)N * DE * 2);
    float* s_emb   = (float*)alloc((size_t)N * DE * 4);
    float* x1      = (float*)alloc((size_t)N * DE * 4);
    float* prel    = (float*)alloc((size_t)NR * DE * 4);
    float* rel2    = (float*)alloc((size_t)NR * DE * 4);
    float* alps    = (float*)alloc((size_t)N * 4);
    float* alpd    = (float*)alloc((size_t)N * 4);
    int*   indptr  = (int*)alloc((size_t)(N + 1) * 4);
    int*   cnt     = (int*)alloc((size_t)N * 4);
    int*   cur     = (int*)alloc((size_t)N * 4);
    int*   adj     = (int*)alloc((size_t)EN * 4);

    dim3 b256(256);

    // CSR build (same edge set both layers -> build once)
    hipMemsetAsync(cnt, 0, (size_t)N * 4, stream);
    hipMemsetAsync(cur, 0, (size_t)N * 4, stream);
    k_count<<<dim3((EN + 255) / 256), b256, 0, stream>>>(ei, E, N, cnt);
    k_scan<<<dim3(1), dim3(1024), 0, stream>>>(cnt, N, indptr);
    k_fill<<<dim3((EN + 255) / 256), b256, 0, stream>>>(ei, E, N, indptr, cur, adj);

    // project tables once (attr table straight to fp16)
    k_gemm<8><<<dim3((NA + 127) / 128), b256, 0, stream>>>(attr_table, NA, femb_w, DE, 0,
        femb_b, nullptr, nullptr, nullptr, nullptr, nullptr, nullptr, nullptr, proj16);
    k_gemm<2><<<dim3((NR + 31) / 32), b256, 0, stream>>>(rel_table, NR, femb_w, DE, 0,
        femb_b, nullptr, nullptr, nullptr, nullptr, nullptr, nullptr, prel, nullptr);
    k_gemm<2><<<dim3((NR + 31) / 32), b256, 0, stream>>>(rel_table, NR, g1w, 2 * DE, DE,
        nullptr, nullptr, nullptr, nullptr, nullptr, nullptr, nullptr, rel2, nullptr);

    // entity attention (h + t fused), 4 nodes per wave
    k_entity<<<dim3((N * 16 + 255) / 256), b256, 0, stream>>>(hA, tA, rix, proj16, prel, s_emb, N);

    // GAT layer 1: h = s_emb @ Wl.T + rel2[r_idx]; alpha fused; h stored fp16
    k_gemm<8><<<dim3((N + 127) / 128), b256, 0, stream>>>(s_emb, N, g1w, 2 * DE, 0,
        nullptr, rel2, rix, g1as, g1ad, alps, alpd, nullptr, h16);
    k_aggregate<<<dim3((N + 3) / 4), b256, 0, stream>>>(indptr, adj, h16, alps, alpd, g1b, x1, N);

    // GAT layer 2
    k_gemm<8><<<dim3((N + 127) / 128), b256, 0, stream>>>(x1, N, g2w, DE, 0,
        nullptr, nullptr, nullptr, g2as, g2ad, alps, alpd, nullptr, h16);
    k_aggregate<<<dim3((N + 3) / 4), b256, 0, stream>>>(indptr, adj, h16, alps, alpd, g2b,
                                                        (float*)d_out, N);
}

// Round 8
// 339.460 us; speedup vs baseline: 1.3955x; 1.3955x over previous
//
#include <hip/hip_runtime.h>
#include <math.h>

#define DE 128
#define NEG_SLOPE 0.2f
#define LOG2E 1.4426950408889634f
#define ESHIFT2 57.707801635559926f  /* 40 * log2(e) */

typedef __attribute__((ext_vector_type(4))) float f4;
typedef __attribute__((ext_vector_type(2))) float f2;
typedef _Float16 half_t;
typedef __attribute__((ext_vector_type(2))) _Float16 h2;
typedef __attribute__((ext_vector_type(4))) _Float16 h4v;
typedef __attribute__((ext_vector_type(8))) _Float16 h8;

// Wave64 sum-reduce on the VALU only (DPP adds + readlane), zero LDS-pipe ops.
__device__ __forceinline__ float wave_red_bcast(float x) {
    union fi { float f; int i; };
    fi a; a.f = x;
    fi t;
    t.i = __builtin_amdgcn_update_dpp(0, a.i, 0x111, 0xf, 0xf, true); a.f += t.f; // row_shr:1
    t.i = __builtin_amdgcn_update_dpp(0, a.i, 0x112, 0xf, 0xf, true); a.f += t.f; // row_shr:2
    t.i = __builtin_amdgcn_update_dpp(0, a.i, 0x114, 0xf, 0xf, true); a.f += t.f; // row_shr:4
    t.i = __builtin_amdgcn_update_dpp(0, a.i, 0x118, 0xf, 0xf, true); a.f += t.f; // row_shr:8
    t.i = __builtin_amdgcn_update_dpp(0, a.i, 0x142, 0xa, 0xf, true); a.f += t.f; // row_bcast:15
    t.i = __builtin_amdgcn_update_dpp(0, a.i, 0x143, 0xc, 0xf, true); a.f += t.f; // row_bcast:31
    fi r; r.i = __builtin_amdgcn_readlane(a.i, 63);
    return r.f;
}

// All-reduce within each 16-lane DPP row (lane gets its row's sum). 4 DPP adds.
__device__ __forceinline__ float row16_allred(float x) {
    union fi { float f; int i; };
    fi a; a.f = x;
    fi t;
    t.i = __builtin_amdgcn_update_dpp(0, a.i, 0x121, 0xf, 0xf, true); a.f += t.f; // row_ror:1
    t.i = __builtin_amdgcn_update_dpp(0, a.i, 0x122, 0xf, 0xf, true); a.f += t.f; // row_ror:2
    t.i = __builtin_amdgcn_update_dpp(0, a.i, 0x124, 0xf, 0xf, true); a.f += t.f; // row_ror:4
    t.i = __builtin_amdgcn_update_dpp(0, a.i, 0x128, 0xf, 0xf, true); a.f += t.f; // row_ror:8
    return a.f;
}

// ---------------------------------------------------------------- CSR build
__global__ __launch_bounds__(256) void k_count(const int* __restrict__ ei, int E, int N,
                                               int* __restrict__ cnt) {
    int e = blockIdx.x * blockDim.x + threadIdx.x;
    int total = E + N;
    if (e >= total) return;
    int dst = (e < E) ? ei[E + e] : (e - E);
    atomicAdd(&cnt[dst], 1);
}

__global__ __launch_bounds__(1024) void k_scan(const int* __restrict__ cnt, int n,
                                               int* __restrict__ indptr) {
    __shared__ int wsum[16];
    __shared__ int btot;
    int tid = threadIdx.x, lane = tid & 63, w = tid >> 6;
    int carry = 0;
    for (int base = 0; base < n; base += 1024) {
        int i = base + tid;
        int v = (i < n) ? cnt[i] : 0;
        int x = v;
#pragma unroll
        for (int off = 1; off < 64; off <<= 1) {
            int t = __shfl_up(x, off, 64);
            if (lane >= off) x += t;
        }
        if (lane == 63) wsum[w] = x;
        __syncthreads();
        if (w == 0) {
            int s = (lane < 16) ? wsum[lane] : 0;
#pragma unroll
            for (int off = 1; off < 16; off <<= 1) {
                int t = __shfl_up(s, off, 64);
                if (lane >= off) s += t;
            }
            if (lane < 16) wsum[lane] = s;
            if (lane == 15) btot = s;
        }
        __syncthreads();
        int wexcl = (w == 0) ? 0 : wsum[w - 1];
        if (i < n) indptr[i] = carry + wexcl + (x - v);
        carry += btot;
        __syncthreads();
    }
    if (tid == 0) indptr[n] = carry;
}

__global__ __launch_bounds__(256) void k_fill(const int* __restrict__ ei, int E, int N,
                                              const int* __restrict__ indptr,
                                              int* __restrict__ cur, int* __restrict__ adj) {
    int e = blockIdx.x * blockDim.x + threadIdx.x;
    int total = E + N;
    if (e >= total) return;
    int src, dst;
    if (e < E) { src = ei[e]; dst = ei[E + e]; }
    else       { src = dst = e - E; }
    int pos = indptr[dst] + atomicAdd(&cur[dst], 1);
    adj[pos] = src;
}

// ---------------------------------------------------------------- small f32 GEMM (500-row rel tables)
template <int RPT>
__global__ __launch_bounds__(256) void k_gemm(const float* __restrict__ in, int rows,
                                              const float* __restrict__ W, int ldw, int wcol0,
                                              const float* __restrict__ bias,
                                              float* __restrict__ out) {
    __shared__ float Wt[128 * 128];
    const int tid = threadIdx.x;
#pragma unroll
    for (int it = 0; it < 16; ++it) {
        int idx = it * 256 + tid;
        int c = idx & 127, k4 = idx >> 7;
        f4 wv = *(const f4*)(W + (size_t)c * ldw + wcol0 + k4 * 4);
#pragma unroll
        for (int j = 0; j < 4; ++j) Wt[(4 * k4 + j) * 128 + c] = wv[j];
    }
    __syncthreads();

    const int cgrp = tid & 15, rgrp = tid >> 4;
    const int c0 = cgrp * 4;
    const int row0 = blockIdx.x * (16 * RPT) + rgrp * RPT;

    const float* rowp[RPT];
#pragma unroll
    for (int i = 0; i < RPT; ++i)
        rowp[i] = in + (size_t)min(row0 + i, rows - 1) * 128;

    float acc[RPT][8];
#pragma unroll
    for (int i = 0; i < RPT; ++i)
#pragma unroll
        for (int j = 0; j < 8; ++j) acc[i][j] = 0.f;

#pragma unroll 1
    for (int k = 0; k < 128; k += 4) {
        f4 a[RPT];
#pragma unroll
        for (int i = 0; i < RPT; ++i) a[i] = *(const f4*)(rowp[i] + k);
#pragma unroll
        for (int kk = 0; kk < 4; ++kk) {
            f4 b0 = *(const f4*)&Wt[(k + kk) * 128 + c0];
            f4 b1 = *(const f4*)&Wt[(k + kk) * 128 + c0 + 64];
#pragma unroll
            for (int i = 0; i < RPT; ++i) {
                float av = a[i][kk];
#pragma unroll
                for (int j = 0; j < 4; ++j) {
                    acc[i][j]     = fmaf(av, b0[j], acc[i][j]);
                    acc[i][j + 4] = fmaf(av, b1[j], acc[i][j + 4]);
                }
            }
        }
    }
    f4 bi0 = {0.f,0.f,0.f,0.f}, bi1 = {0.f,0.f,0.f,0.f};
    if (bias) { bi0 = *(const f4*)(bias + c0); bi1 = *(const f4*)(bias + c0 + 64); }
#pragma unroll
    for (int i = 0; i < RPT; ++i) {
        int r = row0 + i;
        if (r < rows) {
            f4 v0, v1;
#pragma unroll
            for (int j = 0; j < 4; ++j) { v0[j] = acc[i][j] + bi0[j]; v1[j] = acc[i][j+4] + bi1[j]; }
            *(f4*)(out + (size_t)r * 128 + c0) = v0;
            *(f4*)(out + (size_t)r * 128 + c0 + 64) = v1;
        }
    }
}

// ---------------------------------------------------------------- MFMA GEMM (fp16 in, f32 acc)
// out16[r][c] = sum_k A[r][k]*W[c*ldw+wcol0+k] (+bias) (+addtab[addidx[r]]); optional
// fused alpha epilogue als/ald. Block: 64 rows x 128 cols, 4 waves (16 rows each).
// W fp16 in LDS padded to 136 halves/row (stride 17x16B -> conflict-free b128 B-frags).
// D staged through the SAME LDS (f32 [64][132]) for a row-major epilogue.
// Fragment layouts: A lane l -> row l%16, k = 8*(l/16)+j (contiguous 8);
// B lane l -> col l%16, k = 8*(l/16)+j; D lane l -> col l&15, row=(l>>4)*4+reg.
template <typename AT>
__global__ __launch_bounds__(256) void k_gemm_mfma(const AT* __restrict__ A, int rows,
                                                   const float* __restrict__ W, int ldw, int wcol0,
                                                   const float* __restrict__ bias,
                                                   const float* __restrict__ addtab,
                                                   const int* __restrict__ addidx,
                                                   const float* __restrict__ avs,
                                                   const float* __restrict__ avd,
                                                   float* __restrict__ als,
                                                   float* __restrict__ ald,
                                                   half_t* __restrict__ out16) {
    __shared__ alignas(16) char ldsbuf[128 * 136 * 2];  // 34816 B; Dl (33792 B) aliases after sync
    half_t* Wl = (half_t*)ldsbuf;
    float*  Dl = (float*)ldsbuf;

    const int tid = threadIdx.x;
    const int row0 = blockIdx.x * 64;

    // stage W -> fp16 LDS [128][136]
    for (int i = tid * 4; i < 128 * 128; i += 1024) {
        int c = i >> 7, k = i & 127;
        f4 wv = *(const f4*)(W + (size_t)c * ldw + wcol0 + k);
        h4v hv = {(half_t)wv[0], (half_t)wv[1], (half_t)wv[2], (half_t)wv[3]};
        *(h4v*)(Wl + c * 136 + k) = hv;
    }
    __syncthreads();

    const int wv_id = tid >> 6, l = tid & 63, lr = l & 15, lk = l >> 4;
    const int r_a = min(row0 + wv_id * 16 + lr, rows - 1);

    // A fragments: 4 K-steps of 32
    h8 af[4];
#pragma unroll
    for (int ks = 0; ks < 4; ++ks) {
        if constexpr (sizeof(AT) == 4) {
            f4 a0 = *(const f4*)(A + (size_t)r_a * 128 + ks * 32 + lk * 8);
            f4 a1 = *(const f4*)(A + (size_t)r_a * 128 + ks * 32 + lk * 8 + 4);
            h8 v = {(half_t)a0[0], (half_t)a0[1], (half_t)a0[2], (half_t)a0[3],
                    (half_t)a1[0], (half_t)a1[1], (half_t)a1[2], (half_t)a1[3]};
            af[ks] = v;
        } else {
            af[ks] = *(const h8*)(A + (size_t)r_a * 128 + ks * 32 + lk * 8);
        }
    }

    f4 acc[8];
#pragma unroll
    for (int t = 0; t < 8; ++t) acc[t] = (f4){0.f, 0.f, 0.f, 0.f};
#pragma unroll
    for (int ks = 0; ks < 4; ++ks) {
#pragma unroll
        for (int t = 0; t < 8; ++t) {
            h8 bf = *(const h8*)(Wl + (t * 16 + lr) * 136 + ks * 32 + lk * 8);
            acc[t] = __builtin_amdgcn_mfma_f32_16x16x32_f16(af[ks], bf, acc[t], 0, 0, 0);
        }
    }
    __syncthreads();  // all waves done reading Wl before Dl overwrite

    // D -> LDS f32 [64][132]; row = wv*16 + lk*4 + q, col = t*16 + lr
#pragma unroll
    for (int t = 0; t < 8; ++t)
#pragma unroll
        for (int q = 0; q < 4; ++q)
            Dl[(wv_id * 16 + lk * 4 + q) * 132 + t * 16 + lr] = acc[t][q];
    __syncthreads();

    // row-major epilogue: 16 lanes per row, lane owns 8 contiguous cols
    const int cl = (tid & 15) * 8;
    f4 bi0 = {0.f,0.f,0.f,0.f}, bi1 = bi0;
    if (bias) { bi0 = *(const f4*)(bias + cl); bi1 = *(const f4*)(bias + cl + 4); }
    f4 as0 = {0.f,0.f,0.f,0.f}, as1 = as0, ad0 = as0, ad1 = as0;
    if (als) {
        as0 = *(const f4*)(avs + cl); as1 = *(const f4*)(avs + cl + 4);
        ad0 = *(const f4*)(avd + cl); ad1 = *(const f4*)(avd + cl + 4);
    }
#pragma unroll
    for (int pass = 0; pass < 4; ++pass) {
        int lrow = pass * 16 + (tid >> 4);
        int r = row0 + lrow;
        bool ok = r < rows;
        f4 v0 = *(const f4*)(Dl + lrow * 132 + cl);
        f4 v1 = *(const f4*)(Dl + lrow * 132 + cl + 4);
        v0 += bi0; v1 += bi1;
        if (addtab) {
            int ri = addidx[min(r, rows - 1)];
            v0 += *(const f4*)(addtab + (size_t)ri * 128 + cl);
            v1 += *(const f4*)(addtab + (size_t)ri * 128 + cl + 4);
        }
        if (als) {
            float ps = 0.f, pd = 0.f;
#pragma unroll
            for (int j = 0; j < 4; ++j) {
                ps += v0[j] * as0[j] + v1[j] * as1[j];
                pd += v0[j] * ad0[j] + v1[j] * ad1[j];
            }
            ps = row16_allred(ps);
            pd = row16_allred(pd);
            if ((tid & 15) == 0 && ok) { als[r] = ps; ald[r] = pd; }
        }
        if (ok) {
            h8 o = {(half_t)v0[0], (half_t)v0[1], (half_t)v0[2], (half_t)v0[3],
                    (half_t)v1[0], (half_t)v1[1], (half_t)v1[2], (half_t)v1[3]};
            *(h8*)(out16 + (size_t)r * 128 + cl) = o;
        }
    }
}

// ---------------------------------------------------------------- entity attention (r5 structure)
// One wave per node; lane owns cols {2l,2l+1} (4B fp16 gathers). Pure-VALU DPP
// reduce; shift-invariant softmax with fixed shift 40 via exp2. fp16 output.
__global__ __launch_bounds__(256) void k_entity(const int* __restrict__ hA,
                                                const int* __restrict__ tA,
                                                const int* __restrict__ ridx,
                                                const half_t* __restrict__ pattr,
                                                const float* __restrict__ prel,
                                                half_t* __restrict__ s_emb16, int N) {
    int w = (blockIdx.x * blockDim.x + threadIdx.x) >> 6;
    if (w >= N) return;
    w = __builtin_amdgcn_readfirstlane(w);
    const int lane = threadIdx.x & 63;
    const int c = lane * 2;
    const int ri = ridx[w];
    const f2 rp = *(const f2*)(prel + (size_t)ri * 128 + c);
    const float rs0 = rp[0] * LOG2E, rs1 = rp[1] * LOG2E;
    const int* __restrict__ hp = hA + (size_t)w * 16;
    const int* __restrict__ tp = tA + (size_t)w * 16;

    f2 oh = {0.f, 0.f}, ot = {0.f, 0.f};
    float sh = 0.f, st = 0.f;

    h2 bh[2][4], bt[2][4];
#pragma unroll
    for (int q = 0; q < 4; ++q) {
        bh[0][q] = *(const h2*)(pattr + (size_t)hp[q] * 128 + c);
        bt[0][q] = *(const h2*)(pattr + (size_t)tp[q] * 128 + c);
    }
#pragma unroll
    for (int b = 0; b < 4; ++b) {
        const int cur = b & 1, nxt = cur ^ 1;
        if (b < 3) {
#pragma unroll
            for (int q = 0; q < 4; ++q) {
                bh[nxt][q] = *(const h2*)(pattr + (size_t)hp[4 * (b + 1) + q] * 128 + c);
                bt[nxt][q] = *(const h2*)(pattr + (size_t)tp[4 * (b + 1) + q] * 128 + c);
            }
        }
        float fh0[4], fh1[4], ft0[4], ft1[4], pph[4], ppt[4];
#pragma unroll
        for (int q = 0; q < 4; ++q) {
            fh0[q] = (float)bh[cur][q][0]; fh1[q] = (float)bh[cur][q][1];
            ft0[q] = (float)bt[cur][q][0]; ft1[q] = (float)bt[cur][q][1];
            pph[q] = rs0 * fh0[q] + rs1 * fh1[q];
            ppt[q] = rs0 * ft0[q] + rs1 * ft1[q];
        }
        float Sh[4], St[4];
#pragma unroll
        for (int q = 0; q < 4; ++q) {
            Sh[q] = wave_red_bcast(pph[q]);
            St[q] = wave_red_bcast(ppt[q]);
        }
#pragma unroll
        for (int q = 0; q < 4; ++q) {
            float wh = exp2f(Sh[q] - ESHIFT2);
            float wt = exp2f(St[q] - ESHIFT2);
            sh += wh; st += wt;
            oh[0] = fmaf(wh, fh0[q], oh[0]); oh[1] = fmaf(wh, fh1[q], oh[1]);
            ot[0] = fmaf(wt, ft0[q], ot[0]); ot[1] = fmaf(wt, ft1[q], ot[1]);
        }
    }
    float invh = 1.f / sh, invt = 1.f / st;
    h2 hv = {(half_t)(oh[0] * invh + ot[0] * invt),
             (half_t)(oh[1] * invh + ot[1] * invt)};
    *(h2*)(s_emb16 + (size_t)w * 128 + c) = hv;
}

// ---------------------------------------------------------------- GAT aggregate (CSR)
// Wave-uniform edge loop (r5 structure). Output: f32 (out) or fp16 (out16).
__global__ __launch_bounds__(256) void k_aggregate(const int* __restrict__ indptr,
                                                   const int* __restrict__ adj,
                                                   const half_t* __restrict__ hsrc,
                                                   const float* __restrict__ als,
                                                   const float* __restrict__ ald,
                                                   const float* __restrict__ bias,
                                                   float* __restrict__ out,
                                                   half_t* __restrict__ out16, int N) {
    int w = (blockIdx.x * blockDim.x + threadIdx.x) >> 6;
    if (w >= N) return;
    w = __builtin_amdgcn_readfirstlane(w);
    const int lane = threadIdx.x & 63;
    const int c = lane * 2;
    const int beg = indptr[w], end = indptr[w + 1];
    const float adn = ald[w];
    float acc0 = 0.f, acc1 = 0.f, exsum = 0.f;
    int j = beg;
    for (; j + 8 <= end; j += 8) {
        int s[8];
#pragma unroll
        for (int q = 0; q < 8; ++q) s[q] = adj[j + q];
        float ex[8];
#pragma unroll
        for (int q = 0; q < 8; ++q) {
            float e = als[s[q]] + adn;
            e = fmaxf(e, NEG_SLOPE * e);
            ex[q] = __expf(e - 20.f);
        }
        h2 v[8];
#pragma unroll
        for (int q = 0; q < 8; ++q)
            v[q] = *(const h2*)(hsrc + (size_t)s[q] * 128 + c);
#pragma unroll
        for (int q = 0; q < 8; ++q) {
            exsum += ex[q];
            acc0 = fmaf(ex[q], (float)v[q][0], acc0);
            acc1 = fmaf(ex[q], (float)v[q][1], acc1);
        }
    }
    for (; j < end; ++j) {
        int s = adj[j];
        float e = als[s] + adn;
        e = fmaxf(e, NEG_SLOPE * e);
        float ex = __expf(e - 20.f);
        exsum += ex;
        h2 v = *(const h2*)(hsrc + (size_t)s * 128 + c);
        acc0 = fmaf(ex, (float)v[0], acc0);
        acc1 = fmaf(ex, (float)v[1], acc1);
    }
    float inv = 1.f / exsum;
    float o0 = fmaf(acc0, inv, bias[c]);
    float o1 = fmaf(acc1, inv, bias[c + 1]);
    if (out) {
        f2 outv = {o0, o1};
        *(f2*)(out + (size_t)w * 128 + c) = outv;
    } else {
        h2 hv = {(half_t)o0, (half_t)o1};
        *(h2*)(out16 + (size_t)w * 128 + c) = hv;
    }
}

// ---------------------------------------------------------------- launch
extern "C" void kernel_launch(void* const* d_in, const int* in_sizes, int n_in,
                              void* d_out, int out_size, void* d_ws, size_t ws_size,
                              hipStream_t stream) {
    const int*   hA   = (const int*)d_in[0];
    const int*   tA   = (const int*)d_in[1];
    const int*   rix  = (const int*)d_in[2];
    const int*   ei   = (const int*)d_in[3];
    const float* attr_table = (const float*)d_in[4];
    const float* rel_table  = (const float*)d_in[5];
    const float* femb_w = (const float*)d_in[6];
    const float* femb_b = (const float*)d_in[7];
    const float* g1w  = (const float*)d_in[8];
    const float* g1as = (const float*)d_in[9];
    const float* g1ad = (const float*)d_in[10];
    const float* g1b  = (const float*)d_in[11];
    const float* g2w  = (const float*)d_in[12];
    const float* g2as = (const float*)d_in[13];
    const float* g2ad = (const float*)d_in[14];
    const float* g2b  = (const float*)d_in[15];

    const int N  = in_sizes[2];
    const int E  = in_sizes[3] / 2;
    const int NA = in_sizes[4] / DE;
    const int NR = in_sizes[5] / DE;
    const int EN = E + N;

    char* p = (char*)d_ws;
    auto alloc = [&](size_t bytes) -> char* {
        char* q = p;
        p += (bytes + 255) & ~(size_t)255;
        return q;
    };
    half_t* proj16 = (half_t*)alloc((size_t)NA * DE * 2);
    half_t* s16    = (half_t*)alloc((size_t)N * DE * 2);
    half_t* h16    = (half_t*)alloc((size_t)N * DE * 2);
    half_t* x116   = (half_t*)alloc((size_t)N * DE * 2);
    float* prel    = (float*)alloc((size_t)NR * DE * 4);
    float* rel2    = (float*)alloc((size_t)NR * DE * 4);
    float* alps    = (float*)alloc((size_t)N * 4);
    float* alpd    = (float*)alloc((size_t)N * 4);
    int*   indptr  = (int*)alloc((size_t)(N + 1) * 4);
    int*   cnt     = (int*)alloc((size_t)N * 4);
    int*   cur     = (int*)alloc((size_t)N * 4);
    int*   adj     = (int*)alloc((size_t)EN * 4);

    dim3 b256(256);

    // CSR build (same edge set both layers -> build once)
    hipMemsetAsync(cnt, 0, (size_t)N * 4, stream);
    hipMemsetAsync(cur, 0, (size_t)N * 4, stream);
    k_count<<<dim3((EN + 255) / 256), b256, 0, stream>>>(ei, E, N, cnt);
    k_scan<<<dim3(1), dim3(1024), 0, stream>>>(cnt, N, indptr);
    k_fill<<<dim3((EN + 255) / 256), b256, 0, stream>>>(ei, E, N, indptr, cur, adj);

    // rel-table projections (500 rows, f32 path)
    k_gemm<2><<<dim3((NR + 31) / 32), b256, 0, stream>>>(rel_table, NR, femb_w, DE, 0,
                                                         femb_b, prel);
    k_gemm<2><<<dim3((NR + 31) / 32), b256, 0, stream>>>(rel_table, NR, g1w, 2 * DE, DE,
                                                         nullptr, rel2);

    // attr table projection straight to fp16 (MFMA, f32 A-path)
    k_gemm_mfma<float><<<dim3((NA + 63) / 64), b256, 0, stream>>>(attr_table, NA,
        femb_w, DE, 0, femb_b, nullptr, nullptr, nullptr, nullptr, nullptr, nullptr, proj16);

    // entity attention (h + t fused), one node per wave
    k_entity<<<dim3((N + 3) / 4), b256, 0, stream>>>(hA, tA, rix, proj16, prel, s16, N);

    // GAT layer 1: h = s_emb @ Wl.T + rel2[r_idx]; alpha fused; h fp16
    k_gemm_mfma<half_t><<<dim3((N + 63) / 64), b256, 0, stream>>>(s16, N,
        g1w, 2 * DE, 0, nullptr, rel2, rix, g1as, g1ad, alps, alpd, h16);
    k_aggregate<<<dim3((N + 3) / 4), b256, 0, stream>>>(indptr, adj, h16, alps, alpd, g1b,
                                                        nullptr, x116, N);

    // GAT layer 2
    k_gemm_mfma<half_t><<<dim3((N + 63) / 64), b256, 0, stream>>>(x116, N,
        g2w, DE, 0, nullptr, nullptr, nullptr, g2as, g2ad, alps, alpd, h16);
    k_aggregate<<<dim3((N + 3) / 4), b256, 0, stream>>>(indptr, adj, h16, alps, alpd, g2b,
                                                        (float*)d_out, nullptr, N);
}